// Round 7
// baseline (443.010 us; speedup 1.0000x reference)
//
#include <hip/hip_runtime.h>

// (B,T,E,H,HS) = (8,1024,1024,16,64). Inputs/output: float32 (proven r6:
// flag=1 path passed). Internals bf16 MFMA. Host-side ws_size branch:
// fast path (72 MB ws) vs verbatim r6 fallback (64 MB ws).
#define B_  8
#define T_  1024
#define E_  1024
#define H_  16
#define HS_ 64
#define K_  1024

typedef __bf16 bf16x8 __attribute__((ext_vector_type(8)));
typedef float  f32x4  __attribute__((ext_vector_type(4)));
typedef unsigned short us;

__device__ __forceinline__ float bf2f(us u) {
    union { unsigned int i; float f; } c; c.i = ((unsigned int)u) << 16; return c.f;
}
__device__ __forceinline__ us f2bf(float f) {
    union { float f; unsigned int i; } c; c.f = f;
    unsigned int x = c.i;
    return (us)((x + 0x7fff + ((x >> 16) & 1)) >> 16);  // RNE
}
__device__ __forceinline__ bf16x8 cvt8(const float* p) {
    float4 a = *reinterpret_cast<const float4*>(p);
    float4 b = *reinterpret_cast<const float4*>(p + 4);
    union { bf16x8 v; us u[8]; } c;
    c.u[0] = f2bf(a.x); c.u[1] = f2bf(a.y); c.u[2] = f2bf(a.z); c.u[3] = f2bf(a.w);
    c.u[4] = f2bf(b.x); c.u[5] = f2bf(b.y); c.u[6] = f2bf(b.z); c.u[7] = f2bf(b.w);
    return c.v;
}

// Dtype probe (r2/r6-proven). flag=1 => float32 inputs.
__global__ void detect_kernel(const us* __restrict__ x, int* __restrict__ flag) {
    const int t = threadIdx.x;
    int maxe = 0;
    for (int s = 0; s < 8; ++s) {
        us u = x[2 * (t + 256 * s)];
        maxe = max(maxe, (int)((u >> 7) & 0xFF));
    }
    __shared__ int red[256];
    red[t] = maxe;
    __syncthreads();
    for (int off = 128; off > 0; off >>= 1) {
        if (t < off) red[t] = max(red[t], red[t + off]);
        __syncthreads();
    }
    if (t == 0) *flag = (red[0] > 140) ? 1 : 0;
}

// ===========================================================================
// FAST PATH
// ===========================================================================
// One-shot convert (or copy) inputs to bf16 ws. y selects tensor.
__global__ __launch_bounds__(256) void cvt_kernel(
    const void* __restrict__ sx, const void* __restrict__ sq,
    const void* __restrict__ sk, const void* __restrict__ sv,
    const void* __restrict__ sp,
    us* __restrict__ dx, us* __restrict__ dq, us* __restrict__ dk,
    us* __restrict__ dv, us* __restrict__ dp, const int* __restrict__ flagp)
{
    const int y = blockIdx.y;
    const void* src = (y == 0) ? sx : (y == 1) ? sq : (y == 2) ? sk : (y == 3) ? sv : sp;
    us*         dst = (y == 0) ? dx : (y == 1) ? dq : (y == 2) ? dk : (y == 3) ? dv : dp;
    const size_t n = (y == 0) ? (size_t)B_ * T_ * E_ : (size_t)E_ * E_;
    const size_t i = ((size_t)blockIdx.x * 256 + threadIdx.x) * 8;
    if (i >= n) return;
    if (*flagp) *reinterpret_cast<bf16x8*>(dst + i) = cvt8((const float*)src + i);
    else        *reinterpret_cast<bf16x8*>(dst + i) =
                    *reinterpret_cast<const bf16x8*>((const us*)src + i);
}

// 128x128 all-bf16 GEMM (r5/r6 structure). QKV variant: vtrans selects the
// V^T epilogue remap.
__global__ __launch_bounds__(256) void qkv_gf(
    const us* __restrict__ A,
    const us* __restrict__ Wq, const us* __restrict__ Wk, const us* __restrict__ Wv,
    us* __restrict__ q, us* __restrict__ k, us* __restrict__ vT)
{
    const int type = blockIdx.z;
    const us* Bm = (type == 0) ? Wq : (type == 1) ? Wk : Wv;
    us* out      = (type == 0) ? q  : (type == 1) ? k  : vT;
    const int vtrans = (type == 2);

    __shared__ us As[128 * 32];
    __shared__ us Bs[128 * 32];

    const int tid  = threadIdx.x;
    const int lane = tid & 63;
    const int w    = tid >> 6;
    const int quad = lane >> 4;
    const int l15  = lane & 15;
    const int wm   = w >> 1, wn = w & 1;
    const int row0 = blockIdx.x * 128;
    const int col0 = blockIdx.y * 128;

    f32x4 acc[4][4] = {};
    for (int k0 = 0; k0 < K_; k0 += 32) {
        __syncthreads();
#pragma unroll
        for (int i = 0; i < 2; ++i) {
            const int idx = tid + i * 256;
            const int r   = idx >> 2;
            const int c8  = (idx & 3) * 8;
            *reinterpret_cast<bf16x8*>(&As[r * 32 + c8]) =
                *reinterpret_cast<const bf16x8*>(A  + (size_t)(row0 + r) * K_ + k0 + c8);
            *reinterpret_cast<bf16x8*>(&Bs[r * 32 + c8]) =
                *reinterpret_cast<const bf16x8*>(Bm + (size_t)(col0 + r) * K_ + k0 + c8);
        }
        __syncthreads();
        bf16x8 af[4], bf[4];
#pragma unroll
        for (int t = 0; t < 4; ++t) {
            af[t] = *reinterpret_cast<const bf16x8*>(&As[(wm * 64 + t * 16 + l15) * 32 + quad * 8]);
            bf[t] = *reinterpret_cast<const bf16x8*>(&Bs[(wn * 64 + t * 16 + l15) * 32 + quad * 8]);
        }
#pragma unroll
        for (int mt = 0; mt < 4; ++mt)
#pragma unroll
            for (int nt = 0; nt < 4; ++nt)
                acc[mt][nt] = __builtin_amdgcn_mfma_f32_16x16x32_bf16(af[mt], bf[nt], acc[mt][nt], 0, 0, 0);
    }

#pragma unroll
    for (int mt = 0; mt < 4; ++mt)
#pragma unroll
        for (int nt = 0; nt < 4; ++nt)
#pragma unroll
            for (int r = 0; r < 4; ++r) {
                const int m = row0 + wm * 64 + mt * 16 + quad * 4 + r;
                const int n = col0 + wn * 64 + nt * 16 + l15;
                const int b = m >> 10, t = m & 1023;
                const int h = n >> 6,  d = n & 63;
                const us vb = f2bf(acc[mt][nt][r]);
                if (vtrans)  // vT[bh][d][t]
                    out[((size_t)((b * 16 + h) * 64 + d)) * 1024 + t] = vb;
                else         // q/k[bh][t][d]
                    out[((size_t)(b * 16 + h) * 1024 + t) * 64 + d] = vb;
            }
}

// Proj: A bf16 ws, W bf16 ws, C = d_out (f32 or bf16 per flag).
__global__ __launch_bounds__(256) void proj_gf(
    const us* __restrict__ A, const us* __restrict__ Bm, void* __restrict__ C,
    const int* __restrict__ flagp)
{
    __shared__ us As[128 * 32];
    __shared__ us Bs[128 * 32];

    const int tid  = threadIdx.x;
    const int lane = tid & 63;
    const int w    = tid >> 6;
    const int quad = lane >> 4;
    const int l15  = lane & 15;
    const int wm   = w >> 1, wn = w & 1;
    const int row0 = blockIdx.x * 128;
    const int col0 = blockIdx.y * 128;
    const int cf32 = *flagp;

    f32x4 acc[4][4] = {};
    for (int k0 = 0; k0 < K_; k0 += 32) {
        __syncthreads();
#pragma unroll
        for (int i = 0; i < 2; ++i) {
            const int idx = tid + i * 256;
            const int r   = idx >> 2;
            const int c8  = (idx & 3) * 8;
            *reinterpret_cast<bf16x8*>(&As[r * 32 + c8]) =
                *reinterpret_cast<const bf16x8*>(A  + (size_t)(row0 + r) * K_ + k0 + c8);
            *reinterpret_cast<bf16x8*>(&Bs[r * 32 + c8]) =
                *reinterpret_cast<const bf16x8*>(Bm + (size_t)(col0 + r) * K_ + k0 + c8);
        }
        __syncthreads();
        bf16x8 af[4], bf[4];
#pragma unroll
        for (int t = 0; t < 4; ++t) {
            af[t] = *reinterpret_cast<const bf16x8*>(&As[(wm * 64 + t * 16 + l15) * 32 + quad * 8]);
            bf[t] = *reinterpret_cast<const bf16x8*>(&Bs[(wn * 64 + t * 16 + l15) * 32 + quad * 8]);
        }
#pragma unroll
        for (int mt = 0; mt < 4; ++mt)
#pragma unroll
            for (int nt = 0; nt < 4; ++nt)
                acc[mt][nt] = __builtin_amdgcn_mfma_f32_16x16x32_bf16(af[mt], bf[nt], acc[mt][nt], 0, 0, 0);
    }

#pragma unroll
    for (int mt = 0; mt < 4; ++mt)
#pragma unroll
        for (int nt = 0; nt < 4; ++nt)
#pragma unroll
            for (int r = 0; r < 4; ++r) {
                const int m = row0 + wm * 64 + mt * 16 + quad * 4 + r;
                const int n = col0 + wn * 64 + nt * 16 + l15;
                const size_t off = (size_t)m * E_ + n;
                if (cf32) ((float*)C)[off] = acc[mt][nt][r];
                else      ((us*)C)[off] = f2bf(acc[mt][nt][r]);
            }
}

// Barrier-free MFMA flash attention. V pre-transposed in ws: vT[bh][d][t].
// ps is per-wave-private LDS (9 KB/block); K and vT frags straight from global.
#define CSCALE 0.18033688011112042f   // 0.125 * log2(e)

__global__ __launch_bounds__(256) void attn_f(
    const us* __restrict__ Q, const us* __restrict__ K,
    const us* __restrict__ VT, us* __restrict__ O)
{
    const int qt = 15 - blockIdx.x;
    const int bh = blockIdx.y;
    const int q0 = qt * 64;
    const size_t base  = (size_t)bh * T_ * HS_;   // q/k [bh][t][d]
    const size_t baseT = (size_t)bh * HS_ * T_;   // vT  [bh][d][t]
    const int tid  = threadIdx.x;
    const int w    = tid >> 6;
    const int lane = tid & 63;
    const int quad = lane >> 4;
    const int l15  = lane & 15;

    __shared__ __align__(16) us ps[4][16][72];    // per-wave P tile

    bf16x8 qf[2];
    {
        const us* qp = Q + base + (size_t)(q0 + w * 16 + l15) * HS_ + quad * 8;
        qf[0] = *reinterpret_cast<const bf16x8*>(qp);
        qf[1] = *reinterpret_cast<const bf16x8*>(qp + 32);
    }

    float m_i[4], l_i[4];
    f32x4 oacc[4] = {};
#pragma unroll
    for (int r = 0; r < 4; ++r) { m_i[r] = -1e30f; l_i[r] = 0.f; }

    const int nch = qt + 1;
    for (int ch = 0; ch < nch; ++ch) {
        const int s0 = ch * 64;

        // K B-frags: key row s0+nt*16+l15, k(d)=quad*8+j (+32)
        bf16x8 kf[4][2];
#pragma unroll
        for (int nt = 0; nt < 4; ++nt) {
            const us* kp = K + base + (size_t)(s0 + nt * 16 + l15) * HS_ + quad * 8;
            kf[nt][0] = *reinterpret_cast<const bf16x8*>(kp);
            kf[nt][1] = *reinterpret_cast<const bf16x8*>(kp + 32);
        }
        // V^T B-frags: d = nt*16+l15, k(s)=s0+quad*8+j (+32); contiguous 16 B
        bf16x8 vf[4][2];
#pragma unroll
        for (int nt = 0; nt < 4; ++nt) {
            const us* vp = VT + baseT + (size_t)(nt * 16 + l15) * T_ + s0 + quad * 8;
            vf[nt][0] = *reinterpret_cast<const bf16x8*>(vp);
            vf[nt][1] = *reinterpret_cast<const bf16x8*>(vp + 32);
        }

        f32x4 sacc[4] = {};
#pragma unroll
        for (int nt = 0; nt < 4; ++nt) {
            sacc[nt] = __builtin_amdgcn_mfma_f32_16x16x32_bf16(qf[0], kf[nt][0], sacc[nt], 0, 0, 0);
            sacc[nt] = __builtin_amdgcn_mfma_f32_16x16x32_bf16(qf[1], kf[nt][1], sacc[nt], 0, 0, 0);
        }

        const int rowg = q0 + w * 16 + quad * 4;
        if (ch == nch - 1) {
#pragma unroll
            for (int nt = 0; nt < 4; ++nt)
#pragma unroll
                for (int r = 0; r < 4; ++r)
                    if (s0 + nt * 16 + l15 > rowg + r) sacc[nt][r] = -1e30f;
        }

#pragma unroll
        for (int r = 0; r < 4; ++r) {
            float mx = fmaxf(fmaxf(sacc[0][r], sacc[1][r]), fmaxf(sacc[2][r], sacc[3][r]));
            mx = fmaxf(mx, __shfl_xor(mx, 1));
            mx = fmaxf(mx, __shfl_xor(mx, 2));
            mx = fmaxf(mx, __shfl_xor(mx, 4));
            mx = fmaxf(mx, __shfl_xor(mx, 8));
            const float mnew  = fmaxf(m_i[r], mx);
            const float alpha = exp2f((m_i[r] - mnew) * CSCALE);
            m_i[r] = mnew;
            float sum = 0.f;
#pragma unroll
            for (int nt = 0; nt < 4; ++nt) {
                const float p = exp2f((sacc[nt][r] - mnew) * CSCALE);
                sum += p;
                ps[w][quad * 4 + r][nt * 16 + l15] = f2bf(p);
            }
            sum += __shfl_xor(sum, 1);
            sum += __shfl_xor(sum, 2);
            sum += __shfl_xor(sum, 4);
            sum += __shfl_xor(sum, 8);
            l_i[r] = l_i[r] * alpha + sum;
#pragma unroll
            for (int nt = 0; nt < 4; ++nt) oacc[nt][r] *= alpha;
        }

        // P C-layout -> A-layout via per-wave LDS (wave-internal DS ordering)
        bf16x8 pf[2];
        pf[0] = *reinterpret_cast<const bf16x8*>(&ps[w][l15][quad * 8]);
        pf[1] = *reinterpret_cast<const bf16x8*>(&ps[w][l15][quad * 8 + 32]);
#pragma unroll
        for (int nt = 0; nt < 4; ++nt) {
            oacc[nt] = __builtin_amdgcn_mfma_f32_16x16x32_bf16(pf[0], vf[nt][0], oacc[nt], 0, 0, 0);
            oacc[nt] = __builtin_amdgcn_mfma_f32_16x16x32_bf16(pf[1], vf[nt][1], oacc[nt], 0, 0, 0);
        }
    }

    const int b = bh >> 4, h = bh & 15;
    const int trow = q0 + w * 16 + quad * 4;
#pragma unroll
    for (int r = 0; r < 4; ++r) {
        const float inv = 1.f / l_i[r];
        const size_t off = ((size_t)b * T_ + trow + r) * E_ + h * HS_;
#pragma unroll
        for (int nt = 0; nt < 4; ++nt)
            O[off + nt * 16 + l15] = f2bf(oacc[nt][r] * inv);
    }
}

// ===========================================================================
// FALLBACK (r6 verbatim) — used when ws_size < fast-path need
// ===========================================================================
template <int MODE, int F32>
__device__ __forceinline__ void gemm128_body(
    const void* __restrict__ A, const void* __restrict__ Bm, void* __restrict__ out)
{
    __shared__ us As[128 * 32];
    __shared__ us Bs[128 * 32];

    const int tid  = threadIdx.x;
    const int lane = tid & 63;
    const int w    = tid >> 6;
    const int quad = lane >> 4;
    const int l15  = lane & 15;
    const int wm   = w >> 1, wn = w & 1;
    const int row0 = blockIdx.x * 128;
    const int col0 = blockIdx.y * 128;

    f32x4 acc[4][4] = {};
    for (int k0 = 0; k0 < K_; k0 += 32) {
        __syncthreads();
#pragma unroll
        for (int i = 0; i < 2; ++i) {
            const int idx = tid + i * 256;
            const int r   = idx >> 2;
            const int c8  = (idx & 3) * 8;
            bf16x8 av, bv;
            if constexpr (MODE == 0) {
                if constexpr (F32) av = cvt8((const float*)A + (size_t)(row0 + r) * K_ + k0 + c8);
                else av = *reinterpret_cast<const bf16x8*>((const us*)A + (size_t)(row0 + r) * K_ + k0 + c8);
            } else {
                av = *reinterpret_cast<const bf16x8*>((const us*)A + (size_t)(row0 + r) * K_ + k0 + c8);
            }
            if constexpr (F32) bv = cvt8((const float*)Bm + (size_t)(col0 + r) * K_ + k0 + c8);
            else bv = *reinterpret_cast<const bf16x8*>((const us*)Bm + (size_t)(col0 + r) * K_ + k0 + c8);
            *reinterpret_cast<bf16x8*>(&As[r * 32 + c8]) = av;
            *reinterpret_cast<bf16x8*>(&Bs[r * 32 + c8]) = bv;
        }
        __syncthreads();
        bf16x8 af[4], bf[4];
#pragma unroll
        for (int t = 0; t < 4; ++t) {
            af[t] = *reinterpret_cast<const bf16x8*>(&As[(wm * 64 + t * 16 + l15) * 32 + quad * 8]);
            bf[t] = *reinterpret_cast<const bf16x8*>(&Bs[(wn * 64 + t * 16 + l15) * 32 + quad * 8]);
        }
#pragma unroll
        for (int mt = 0; mt < 4; ++mt)
#pragma unroll
            for (int nt = 0; nt < 4; ++nt)
                acc[mt][nt] = __builtin_amdgcn_mfma_f32_16x16x32_bf16(af[mt], bf[nt], acc[mt][nt], 0, 0, 0);
    }
#pragma unroll
    for (int mt = 0; mt < 4; ++mt)
#pragma unroll
        for (int nt = 0; nt < 4; ++nt)
#pragma unroll
            for (int r = 0; r < 4; ++r) {
                const int m = row0 + wm * 64 + mt * 16 + quad * 4 + r;
                const int n = col0 + wn * 64 + nt * 16 + l15;
                const float val = acc[mt][nt][r];
                if constexpr (MODE == 0) {
                    const int b = m >> 10, t = m & 1023;
                    const int h = n >> 6,  d = n & 63;
                    ((us*)out)[((size_t)(b * 16 + h) * 1024 + t) * 64 + d] = f2bf(val);
                } else {
                    if constexpr (F32) ((float*)out)[(size_t)m * E_ + n] = val;
                    else               ((us*)out)[(size_t)m * E_ + n] = f2bf(val);
                }
            }
}

__global__ __launch_bounds__(256) void qkv_g(
    const void* __restrict__ x,
    const void* __restrict__ Wq, const void* __restrict__ Wk, const void* __restrict__ Wv,
    us* __restrict__ q, us* __restrict__ k, us* __restrict__ v,
    const int* __restrict__ flagp)
{
    const int type = blockIdx.z;
    const void* W = (type == 0) ? Wq : (type == 1) ? Wk : Wv;
    us* out       = (type == 0) ? q  : (type == 1) ? k  : v;
    if (*flagp) gemm128_body<0, 1>(x, W, out);
    else        gemm128_body<0, 0>(x, W, out);
}

__global__ __launch_bounds__(256) void proj_g(
    const us* __restrict__ A, const void* __restrict__ W, void* __restrict__ C,
    const int* __restrict__ flagp)
{
    if (*flagp) gemm128_body<1, 1>(A, W, C);
    else        gemm128_body<1, 0>(A, W, C);
}

__global__ __launch_bounds__(256) void attn_m(
    const us* __restrict__ Q, const us* __restrict__ K,
    const us* __restrict__ V, us* __restrict__ O)
{
    const int qt = 15 - blockIdx.x;
    const int bh = blockIdx.y;
    const int q0 = qt * 64;
    const size_t base = (size_t)bh * T_ * HS_;
    const int tid  = threadIdx.x;
    const int w    = tid >> 6;
    const int lane = tid & 63;
    const int quad = lane >> 4;
    const int l15  = lane & 15;

    __shared__ __align__(16) us vt[64][72];
    __shared__ __align__(16) us ps[4][16][72];

    bf16x8 qf[2];
    {
        const us* qp = Q + base + (size_t)(q0 + w * 16 + l15) * HS_ + quad * 8;
        qf[0] = *reinterpret_cast<const bf16x8*>(qp);
        qf[1] = *reinterpret_cast<const bf16x8*>(qp + 32);
    }

    float m_i[4], l_i[4];
    f32x4 oacc[4] = {};
#pragma unroll
    for (int r = 0; r < 4; ++r) { m_i[r] = -1e30f; l_i[r] = 0.f; }

    const int vs  = lane;
    const int vd0 = w * 16;
    const int nch = qt + 1;
    for (int ch = 0; ch < nch; ++ch) {
        const int s0 = ch * 64;
        __syncthreads();
        {
            const us* vp = V + base + (size_t)(s0 + vs) * HS_ + vd0;
            union { bf16x8 v; us u[8]; } a, b;
            a.v = *reinterpret_cast<const bf16x8*>(vp);
            b.v = *reinterpret_cast<const bf16x8*>(vp + 8);
#pragma unroll
            for (int j = 0; j < 8; ++j) vt[vd0 + j][vs]     = a.u[j];
#pragma unroll
            for (int j = 0; j < 8; ++j) vt[vd0 + 8 + j][vs] = b.u[j];
        }
        bf16x8 kf[4][2];
#pragma unroll
        for (int nt = 0; nt < 4; ++nt) {
            const us* kp = K + base + (size_t)(s0 + nt * 16 + l15) * HS_ + quad * 8;
            kf[nt][0] = *reinterpret_cast<const bf16x8*>(kp);
            kf[nt][1] = *reinterpret_cast<const bf16x8*>(kp + 32);
        }
        f32x4 sacc[4] = {};
#pragma unroll
        for (int nt = 0; nt < 4; ++nt) {
            sacc[nt] = __builtin_amdgcn_mfma_f32_16x16x32_bf16(qf[0], kf[nt][0], sacc[nt], 0, 0, 0);
            sacc[nt] = __builtin_amdgcn_mfma_f32_16x16x32_bf16(qf[1], kf[nt][1], sacc[nt], 0, 0, 0);
        }
        __syncthreads();
        const int rowg = q0 + w * 16 + quad * 4;
        if (ch == nch - 1) {
#pragma unroll
            for (int nt = 0; nt < 4; ++nt)
#pragma unroll
                for (int r = 0; r < 4; ++r)
                    if (s0 + nt * 16 + l15 > rowg + r) sacc[nt][r] = -1e30f;
        }
#pragma unroll
        for (int r = 0; r < 4; ++r) {
            float mx = fmaxf(fmaxf(sacc[0][r], sacc[1][r]), fmaxf(sacc[2][r], sacc[3][r]));
            mx = fmaxf(mx, __shfl_xor(mx, 1));
            mx = fmaxf(mx, __shfl_xor(mx, 2));
            mx = fmaxf(mx, __shfl_xor(mx, 4));
            mx = fmaxf(mx, __shfl_xor(mx, 8));
            const float mnew  = fmaxf(m_i[r], mx);
            const float alpha = exp2f((m_i[r] - mnew) * CSCALE);
            m_i[r] = mnew;
            float sum = 0.f;
#pragma unroll
            for (int nt = 0; nt < 4; ++nt) {
                const float p = exp2f((sacc[nt][r] - mnew) * CSCALE);
                sum += p;
                ps[w][quad * 4 + r][nt * 16 + l15] = f2bf(p);
            }
            sum += __shfl_xor(sum, 1);
            sum += __shfl_xor(sum, 2);
            sum += __shfl_xor(sum, 4);
            sum += __shfl_xor(sum, 8);
            l_i[r] = l_i[r] * alpha + sum;
#pragma unroll
            for (int nt = 0; nt < 4; ++nt) oacc[nt][r] *= alpha;
        }
        bf16x8 pf[2];
        pf[0] = *reinterpret_cast<const bf16x8*>(&ps[w][l15][quad * 8]);
        pf[1] = *reinterpret_cast<const bf16x8*>(&ps[w][l15][quad * 8 + 32]);
#pragma unroll
        for (int nt = 0; nt < 4; ++nt) {
            bf16x8 vf0 = *reinterpret_cast<const bf16x8*>(&vt[nt * 16 + l15][quad * 8]);
            bf16x8 vf1 = *reinterpret_cast<const bf16x8*>(&vt[nt * 16 + l15][quad * 8 + 32]);
            oacc[nt] = __builtin_amdgcn_mfma_f32_16x16x32_bf16(pf[0], vf0, oacc[nt], 0, 0, 0);
            oacc[nt] = __builtin_amdgcn_mfma_f32_16x16x32_bf16(pf[1], vf1, oacc[nt], 0, 0, 0);
        }
    }
    const int b = bh >> 4, h = bh & 15;
    const int trow = q0 + w * 16 + quad * 4;
#pragma unroll
    for (int r = 0; r < 4; ++r) {
        const float inv = 1.f / l_i[r];
        const size_t off = ((size_t)b * T_ + trow + r) * E_ + h * HS_;
#pragma unroll
        for (int nt = 0; nt < 4; ++nt)
            O[off + nt * 16 + l15] = f2bf(oacc[nt][r] * inv);
    }
}

// ===========================================================================
extern "C" void kernel_launch(void* const* d_in, const int* in_sizes, int n_in,
                              void* d_out, int out_size, void* d_ws, size_t ws_size,
                              hipStream_t stream) {
    // setup_inputs order: x, Wk, Wq, Wv, Wproj, i
    const void* x  = d_in[0];
    const void* Wk = d_in[1];
    const void* Wq = d_in[2];
    const void* Wv = d_in[3];
    const void* Wp = d_in[4];

    const size_t qe = (size_t)B_ * H_ * T_ * HS_;   // 8,388,608 elems
    const size_t we = (size_t)E_ * E_;              // 1,048,576 elems
    int* flag = (int*)d_ws;

    // fast ws: flag | xb(16M, reused as o) | wq | wk | wv | wp | q | k | vT
    const size_t NEED_FAST = 256 + (4 * qe + 4 * we) * sizeof(us);   // ~72 MB

    detect_kernel<<<1, 256, 0, stream>>>((const us*)x, flag);

    if (ws_size >= NEED_FAST) {
        us* xb = (us*)((char*)d_ws + 256);
        us* wq = xb + qe;
        us* wk = wq + we;
        us* wv = wk + we;
        us* wp = wv + we;
        us* q  = wp + we;
        us* k  = q + qe;
        us* vT = k + qe;
        us* o  = xb;   // xb dead after qkv_gf

        cvt_kernel<<<dim3(4096, 5), 256, 0, stream>>>(x, Wq, Wk, Wv, Wp,
                                                      xb, wq, wk, wv, wp, flag);
        qkv_gf<<<dim3(64, 8, 3), 256, 0, stream>>>(xb, wq, wk, wv, q, k, vT);
        attn_f<<<dim3(16, 128), 256, 0, stream>>>(q, k, vT, o);
        proj_gf<<<dim3(64, 8), 256, 0, stream>>>(o, wp, d_out, flag);
    } else {
        // r6 fallback (64 MB ws)
        us* q = (us*)((char*)d_ws + 256);
        us* k = q + qe;
        us* v = k + qe;
        us* o = v + qe;
        qkv_g<<<dim3(64, 8, 3), 256, 0, stream>>>(x, Wq, Wk, Wv, q, k, v, flag);
        attn_m<<<dim3(16, 128), 256, 0, stream>>>(q, k, v, o);
        proj_g<<<dim3(64, 8), 256, 0, stream>>>(o, Wp, d_out, flag);
    }
}

// Round 8
// 343.401 us; speedup vs baseline: 1.2901x; 1.2901x over previous
//
#include <hip/hip_runtime.h>

// (B,T,E,H,HS) = (8,1024,1024,16,64). Inputs/output: float32 (r6/r7-proven,
// flag=1 path). Internals bf16 MFMA. Fast path needs ~72 MB ws; r6-verbatim
// fallback otherwise.
#define B_  8
#define T_  1024
#define E_  1024
#define H_  16
#define HS_ 64
#define K_  1024

typedef __bf16 bf16x8 __attribute__((ext_vector_type(8)));
typedef float  f32x4  __attribute__((ext_vector_type(4)));
typedef unsigned short us;

__device__ __forceinline__ float bf2f(us u) {
    union { unsigned int i; float f; } c; c.i = ((unsigned int)u) << 16; return c.f;
}
__device__ __forceinline__ us f2bf(float f) {
    union { float f; unsigned int i; } c; c.f = f;
    unsigned int x = c.i;
    return (us)((x + 0x7fff + ((x >> 16) & 1)) >> 16);  // RNE
}
__device__ __forceinline__ bf16x8 cvt8(const float* p) {
    float4 a = *reinterpret_cast<const float4*>(p);
    float4 b = *reinterpret_cast<const float4*>(p + 4);
    union { bf16x8 v; us u[8]; } c;
    c.u[0] = f2bf(a.x); c.u[1] = f2bf(a.y); c.u[2] = f2bf(a.z); c.u[3] = f2bf(a.w);
    c.u[4] = f2bf(b.x); c.u[5] = f2bf(b.y); c.u[6] = f2bf(b.z); c.u[7] = f2bf(b.w);
    return c.v;
}
// Async global->LDS 16B/lane. LDS dest must be wave-uniform base + lane*16
// (m97/m104); all call sites below satisfy this.
__device__ __forceinline__ void async_cp16(const us* g, us* l) {
    __builtin_amdgcn_global_load_lds((const unsigned int*)g, (unsigned int*)l, 16, 0, 0);
}

// Dtype probe (r2/r6-proven). flag=1 => float32 inputs.
__global__ void detect_kernel(const us* __restrict__ x, int* __restrict__ flag) {
    const int t = threadIdx.x;
    int maxe = 0;
    for (int s = 0; s < 8; ++s) {
        us u = x[2 * (t + 256 * s)];
        maxe = max(maxe, (int)((u >> 7) & 0xFF));
    }
    __shared__ int red[256];
    red[t] = maxe;
    __syncthreads();
    for (int off = 128; off > 0; off >>= 1) {
        if (t < off) red[t] = max(red[t], red[t + off]);
        __syncthreads();
    }
    if (t == 0) *flag = (red[0] > 140) ? 1 : 0;
}

// ===========================================================================
// FAST PATH
// ===========================================================================
__global__ __launch_bounds__(256) void cvt_kernel(
    const void* __restrict__ sx, const void* __restrict__ sq,
    const void* __restrict__ sk, const void* __restrict__ sv,
    const void* __restrict__ sp,
    us* __restrict__ dx, us* __restrict__ dq, us* __restrict__ dk,
    us* __restrict__ dv, us* __restrict__ dp, const int* __restrict__ flagp)
{
    const int y = blockIdx.y;
    const void* src = (y == 0) ? sx : (y == 1) ? sq : (y == 2) ? sk : (y == 3) ? sv : sp;
    us*         dst = (y == 0) ? dx : (y == 1) ? dq : (y == 2) ? dk : (y == 3) ? dv : dp;
    const size_t n = (y == 0) ? (size_t)B_ * T_ * E_ : (size_t)E_ * E_;
    const size_t i = ((size_t)blockIdx.x * 256 + threadIdx.x) * 8;
    if (i >= n) return;
    if (*flagp) *reinterpret_cast<bf16x8*>(dst + i) = cvt8((const float*)src + i);
    else        *reinterpret_cast<bf16x8*>(dst + i) =
                    *reinterpret_cast<const bf16x8*>((const us*)src + i);
}

// 128x128 all-bf16 GEMM with global_load_lds width-16 staging (m97 pattern).
// QKV variant: type 2 writes V transposed (vT[bh][d][t]).
__global__ __launch_bounds__(256) void qkv_gf(
    const us* __restrict__ A,
    const us* __restrict__ Wq, const us* __restrict__ Wk, const us* __restrict__ Wv,
    us* __restrict__ q, us* __restrict__ k, us* __restrict__ vT)
{
    const int type = blockIdx.z;
    const us* Bm = (type == 0) ? Wq : (type == 1) ? Wk : Wv;
    us* out      = (type == 0) ? q  : (type == 1) ? k  : vT;
    const int vtrans = (type == 2);

    __shared__ us As[128 * 32];
    __shared__ us Bs[128 * 32];

    const int tid  = threadIdx.x;
    const int lane = tid & 63;
    const int w    = tid >> 6;
    const int quad = lane >> 4;
    const int l15  = lane & 15;
    const int wm   = w >> 1, wn = w & 1;
    const int row0 = blockIdx.x * 128;
    const int col0 = blockIdx.y * 128;

    f32x4 acc[4][4] = {};
    for (int k0 = 0; k0 < K_; k0 += 32) {
        __syncthreads();
#pragma unroll
        for (int i = 0; i < 2; ++i) {
            const int idx = tid + i * 256;       // 0..511; LDS addr = idx*16B
            const int r   = idx >> 2;            // 0..127
            const int c8  = (idx & 3) * 8;
            async_cp16(A  + (size_t)(row0 + r) * K_ + k0 + c8, &As[r * 32 + c8]);
            async_cp16(Bm + (size_t)(col0 + r) * K_ + k0 + c8, &Bs[r * 32 + c8]);
        }
        __syncthreads();   // compiler drains vmcnt before barrier
        bf16x8 af[4], bf[4];
#pragma unroll
        for (int t = 0; t < 4; ++t) {
            af[t] = *reinterpret_cast<const bf16x8*>(&As[(wm * 64 + t * 16 + l15) * 32 + quad * 8]);
            bf[t] = *reinterpret_cast<const bf16x8*>(&Bs[(wn * 64 + t * 16 + l15) * 32 + quad * 8]);
        }
#pragma unroll
        for (int mt = 0; mt < 4; ++mt)
#pragma unroll
            for (int nt = 0; nt < 4; ++nt)
                acc[mt][nt] = __builtin_amdgcn_mfma_f32_16x16x32_bf16(af[mt], bf[nt], acc[mt][nt], 0, 0, 0);
    }

#pragma unroll
    for (int mt = 0; mt < 4; ++mt)
#pragma unroll
        for (int nt = 0; nt < 4; ++nt)
#pragma unroll
            for (int r = 0; r < 4; ++r) {
                const int m = row0 + wm * 64 + mt * 16 + quad * 4 + r;
                const int n = col0 + wn * 64 + nt * 16 + l15;
                const int b = m >> 10, t = m & 1023;
                const int h = n >> 6,  d = n & 63;
                const us vb = f2bf(acc[mt][nt][r]);
                if (vtrans)  out[((size_t)((b * 16 + h) * 64 + d)) * 1024 + t] = vb;
                else         out[((size_t)(b * 16 + h) * 1024 + t) * 64 + d] = vb;
            }
}

__global__ __launch_bounds__(256) void proj_gf(
    const us* __restrict__ A, const us* __restrict__ Bm, void* __restrict__ C,
    const int* __restrict__ flagp)
{
    __shared__ us As[128 * 32];
    __shared__ us Bs[128 * 32];

    const int tid  = threadIdx.x;
    const int lane = tid & 63;
    const int w    = tid >> 6;
    const int quad = lane >> 4;
    const int l15  = lane & 15;
    const int wm   = w >> 1, wn = w & 1;
    const int row0 = blockIdx.x * 128;
    const int col0 = blockIdx.y * 128;
    const int cf32 = *flagp;

    f32x4 acc[4][4] = {};
    for (int k0 = 0; k0 < K_; k0 += 32) {
        __syncthreads();
#pragma unroll
        for (int i = 0; i < 2; ++i) {
            const int idx = tid + i * 256;
            const int r   = idx >> 2;
            const int c8  = (idx & 3) * 8;
            async_cp16(A  + (size_t)(row0 + r) * K_ + k0 + c8, &As[r * 32 + c8]);
            async_cp16(Bm + (size_t)(col0 + r) * K_ + k0 + c8, &Bs[r * 32 + c8]);
        }
        __syncthreads();
        bf16x8 af[4], bf[4];
#pragma unroll
        for (int t = 0; t < 4; ++t) {
            af[t] = *reinterpret_cast<const bf16x8*>(&As[(wm * 64 + t * 16 + l15) * 32 + quad * 8]);
            bf[t] = *reinterpret_cast<const bf16x8*>(&Bs[(wn * 64 + t * 16 + l15) * 32 + quad * 8]);
        }
#pragma unroll
        for (int mt = 0; mt < 4; ++mt)
#pragma unroll
            for (int nt = 0; nt < 4; ++nt)
                acc[mt][nt] = __builtin_amdgcn_mfma_f32_16x16x32_bf16(af[mt], bf[nt], acc[mt][nt], 0, 0, 0);
    }

#pragma unroll
    for (int mt = 0; mt < 4; ++mt)
#pragma unroll
        for (int nt = 0; nt < 4; ++nt)
#pragma unroll
            for (int r = 0; r < 4; ++r) {
                const int m = row0 + wm * 64 + mt * 16 + quad * 4 + r;
                const int n = col0 + wn * 64 + nt * 16 + l15;
                const size_t off = (size_t)m * E_ + n;
                if (cf32) ((float*)C)[off] = acc[mt][nt][r];
                else      ((us*)C)[off] = f2bf(acc[mt][nt][r]);
            }
}

// MFMA flash attention v3: 128 Q rows/block (wave = 32 rows, 2 m-frags);
// 64-key chunks; K and V (pre-transposed vT) staged cooperatively in LDS.
#define CSCALE 0.18033688011112042f   // 0.125 * log2(e)

__global__ __launch_bounds__(256) void attn_v3(
    const us* __restrict__ Q, const us* __restrict__ K,
    const us* __restrict__ VT, us* __restrict__ O)
{
    const int qt = 7 - blockIdx.x;      // heavy tiles first
    const int bh = blockIdx.y;
    const int q0 = qt * 128;
    const size_t base  = (size_t)bh * T_ * HS_;   // q/k [bh][t][d]
    const size_t baseT = (size_t)bh * HS_ * T_;   // vT  [bh][d][t]
    const int tid  = threadIdx.x;
    const int w    = tid >> 6;
    const int lane = tid & 63;
    const int quad = lane >> 4;
    const int l15  = lane & 15;

    __shared__ __align__(16) us kt[64][72];     // K chunk [s][d]
    __shared__ __align__(16) us vt[64][72];     // V^T chunk [d][s]
    __shared__ __align__(16) us ps[4][32][72];  // per-wave P [qrow][key]

    // Q A-frags: rows q0 + w*32 + mt*16 + l15
    bf16x8 qf[2][2];
#pragma unroll
    for (int mt = 0; mt < 2; ++mt) {
        const us* qp = Q + base + (size_t)(q0 + w * 32 + mt * 16 + l15) * HS_ + quad * 8;
        qf[mt][0] = *reinterpret_cast<const bf16x8*>(qp);
        qf[mt][1] = *reinterpret_cast<const bf16x8*>(qp + 32);
    }

    float m_i[2][4], l_i[2][4];
    f32x4 oacc[2][4] = {};
#pragma unroll
    for (int mt = 0; mt < 2; ++mt)
#pragma unroll
        for (int r = 0; r < 4; ++r) { m_i[mt][r] = -1e30f; l_i[mt][r] = 0.f; }

    const int rowlo = q0 + w * 32;      // this wave's lowest row
    const int nch = 2 * qt + 2;
    for (int ch = 0; ch < nch; ++ch) {
        const int s0 = ch * 64;
        __syncthreads();                // prior chunk's LDS readers done
#pragma unroll
        for (int i = 0; i < 2; ++i) {   // stage 64x64 K and V^T chunks
            const int idx = tid + i * 256;   // 0..511
            const int r   = idx >> 3;        // 0..63
            const int c8  = (idx & 7) * 8;   // 0..56
            *reinterpret_cast<bf16x8*>(&kt[r][c8]) =
                *reinterpret_cast<const bf16x8*>(K + base + (size_t)(s0 + r) * HS_ + c8);
            *reinterpret_cast<bf16x8*>(&vt[r][c8]) =
                *reinterpret_cast<const bf16x8*>(VT + baseT + (size_t)r * T_ + s0 + c8);
        }
        __syncthreads();

        if (s0 <= rowlo + 31) {         // wave has unmasked keys in this chunk
            // ---- S = Q.K^T
            f32x4 sacc[2][4] = {};
#pragma unroll
            for (int nt = 0; nt < 4; ++nt) {
                bf16x8 kf0 = *reinterpret_cast<const bf16x8*>(&kt[nt * 16 + l15][quad * 8]);
                bf16x8 kf1 = *reinterpret_cast<const bf16x8*>(&kt[nt * 16 + l15][quad * 8 + 32]);
#pragma unroll
                for (int mt = 0; mt < 2; ++mt) {
                    sacc[mt][nt] = __builtin_amdgcn_mfma_f32_16x16x32_bf16(qf[mt][0], kf0, sacc[mt][nt], 0, 0, 0);
                    sacc[mt][nt] = __builtin_amdgcn_mfma_f32_16x16x32_bf16(qf[mt][1], kf1, sacc[mt][nt], 0, 0, 0);
                }
            }
            // ---- causal mask (diagonal-overlapping chunks only)
            if (s0 + 63 > rowlo) {
#pragma unroll
                for (int mt = 0; mt < 2; ++mt)
#pragma unroll
                    for (int nt = 0; nt < 4; ++nt)
#pragma unroll
                        for (int r = 0; r < 4; ++r)
                            if (s0 + nt * 16 + l15 > rowlo + mt * 16 + quad * 4 + r)
                                sacc[mt][nt][r] = -1e30f;
            }
            // ---- online softmax
#pragma unroll
            for (int mt = 0; mt < 2; ++mt)
#pragma unroll
                for (int r = 0; r < 4; ++r) {
                    float mx = fmaxf(fmaxf(sacc[mt][0][r], sacc[mt][1][r]),
                                     fmaxf(sacc[mt][2][r], sacc[mt][3][r]));
                    mx = fmaxf(mx, __shfl_xor(mx, 1));
                    mx = fmaxf(mx, __shfl_xor(mx, 2));
                    mx = fmaxf(mx, __shfl_xor(mx, 4));
                    mx = fmaxf(mx, __shfl_xor(mx, 8));
                    const float mnew  = fmaxf(m_i[mt][r], mx);
                    const float alpha = exp2f((m_i[mt][r] - mnew) * CSCALE);
                    m_i[mt][r] = mnew;
                    float sum = 0.f;
#pragma unroll
                    for (int nt = 0; nt < 4; ++nt) {
                        const float p = exp2f((sacc[mt][nt][r] - mnew) * CSCALE);
                        sum += p;
                        ps[w][mt * 16 + quad * 4 + r][nt * 16 + l15] = f2bf(p);
                    }
                    sum += __shfl_xor(sum, 1);
                    sum += __shfl_xor(sum, 2);
                    sum += __shfl_xor(sum, 4);
                    sum += __shfl_xor(sum, 8);
                    l_i[mt][r] = l_i[mt][r] * alpha + sum;
#pragma unroll
                    for (int dt = 0; dt < 4; ++dt) oacc[mt][dt][r] *= alpha;
                }
            // ---- O += P.V  (P via per-wave LDS round-trip; wave-internal order)
            bf16x8 pf[2][2];
#pragma unroll
            for (int mt = 0; mt < 2; ++mt) {
                pf[mt][0] = *reinterpret_cast<const bf16x8*>(&ps[w][mt * 16 + l15][quad * 8]);
                pf[mt][1] = *reinterpret_cast<const bf16x8*>(&ps[w][mt * 16 + l15][quad * 8 + 32]);
            }
#pragma unroll
            for (int dt = 0; dt < 4; ++dt) {
                bf16x8 vf0 = *reinterpret_cast<const bf16x8*>(&vt[dt * 16 + l15][quad * 8]);
                bf16x8 vf1 = *reinterpret_cast<const bf16x8*>(&vt[dt * 16 + l15][quad * 8 + 32]);
#pragma unroll
                for (int mt = 0; mt < 2; ++mt) {
                    oacc[mt][dt] = __builtin_amdgcn_mfma_f32_16x16x32_bf16(pf[mt][0], vf0, oacc[mt][dt], 0, 0, 0);
                    oacc[mt][dt] = __builtin_amdgcn_mfma_f32_16x16x32_bf16(pf[mt][1], vf1, oacc[mt][dt], 0, 0, 0);
                }
            }
        }
    }

    // epilogue: normalize, concat-head bf16 ws [b][t][h*HS+d]
    const int b = bh >> 4, h = bh & 15;
#pragma unroll
    for (int mt = 0; mt < 2; ++mt)
#pragma unroll
        for (int r = 0; r < 4; ++r) {
            const int row = q0 + w * 32 + mt * 16 + quad * 4 + r;
            const float inv = 1.f / l_i[mt][r];
            const size_t off = ((size_t)b * T_ + row) * E_ + h * HS_;
#pragma unroll
            for (int dt = 0; dt < 4; ++dt)
                O[off + dt * 16 + l15] = f2bf(oacc[mt][dt][r] * inv);
        }
}

// ===========================================================================
// FALLBACK (r6 verbatim) — used when ws_size < fast-path need
// ===========================================================================
template <int MODE, int F32>
__device__ __forceinline__ void gemm128_body(
    const void* __restrict__ A, const void* __restrict__ Bm, void* __restrict__ out)
{
    __shared__ us As[128 * 32];
    __shared__ us Bs[128 * 32];

    const int tid  = threadIdx.x;
    const int lane = tid & 63;
    const int w    = tid >> 6;
    const int quad = lane >> 4;
    const int l15  = lane & 15;
    const int wm   = w >> 1, wn = w & 1;
    const int row0 = blockIdx.x * 128;
    const int col0 = blockIdx.y * 128;

    f32x4 acc[4][4] = {};
    for (int k0 = 0; k0 < K_; k0 += 32) {
        __syncthreads();
#pragma unroll
        for (int i = 0; i < 2; ++i) {
            const int idx = tid + i * 256;
            const int r   = idx >> 2;
            const int c8  = (idx & 3) * 8;
            bf16x8 av, bv;
            if constexpr (MODE == 0) {
                if constexpr (F32) av = cvt8((const float*)A + (size_t)(row0 + r) * K_ + k0 + c8);
                else av = *reinterpret_cast<const bf16x8*>((const us*)A + (size_t)(row0 + r) * K_ + k0 + c8);
            } else {
                av = *reinterpret_cast<const bf16x8*>((const us*)A + (size_t)(row0 + r) * K_ + k0 + c8);
            }
            if constexpr (F32) bv = cvt8((const float*)Bm + (size_t)(col0 + r) * K_ + k0 + c8);
            else bv = *reinterpret_cast<const bf16x8*>((const us*)Bm + (size_t)(col0 + r) * K_ + k0 + c8);
            *reinterpret_cast<bf16x8*>(&As[r * 32 + c8]) = av;
            *reinterpret_cast<bf16x8*>(&Bs[r * 32 + c8]) = bv;
        }
        __syncthreads();
        bf16x8 af[4], bf[4];
#pragma unroll
        for (int t = 0; t < 4; ++t) {
            af[t] = *reinterpret_cast<const bf16x8*>(&As[(wm * 64 + t * 16 + l15) * 32 + quad * 8]);
            bf[t] = *reinterpret_cast<const bf16x8*>(&Bs[(wn * 64 + t * 16 + l15) * 32 + quad * 8]);
        }
#pragma unroll
        for (int mt = 0; mt < 4; ++mt)
#pragma unroll
            for (int nt = 0; nt < 4; ++nt)
                acc[mt][nt] = __builtin_amdgcn_mfma_f32_16x16x32_bf16(af[mt], bf[nt], acc[mt][nt], 0, 0, 0);
    }
#pragma unroll
    for (int mt = 0; mt < 4; ++mt)
#pragma unroll
        for (int nt = 0; nt < 4; ++nt)
#pragma unroll
            for (int r = 0; r < 4; ++r) {
                const int m = row0 + wm * 64 + mt * 16 + quad * 4 + r;
                const int n = col0 + wn * 64 + nt * 16 + l15;
                const float val = acc[mt][nt][r];
                if constexpr (MODE == 0) {
                    const int b = m >> 10, t = m & 1023;
                    const int h = n >> 6,  d = n & 63;
                    ((us*)out)[((size_t)(b * 16 + h) * 1024 + t) * 64 + d] = f2bf(val);
                } else {
                    if constexpr (F32) ((float*)out)[(size_t)m * E_ + n] = val;
                    else               ((us*)out)[(size_t)m * E_ + n] = f2bf(val);
                }
            }
}

__global__ __launch_bounds__(256) void qkv_g(
    const void* __restrict__ x,
    const void* __restrict__ Wq, const void* __restrict__ Wk, const void* __restrict__ Wv,
    us* __restrict__ q, us* __restrict__ k, us* __restrict__ v,
    const int* __restrict__ flagp)
{
    const int type = blockIdx.z;
    const void* W = (type == 0) ? Wq : (type == 1) ? Wk : Wv;
    us* out       = (type == 0) ? q  : (type == 1) ? k  : v;
    if (*flagp) gemm128_body<0, 1>(x, W, out);
    else        gemm128_body<0, 0>(x, W, out);
}

__global__ __launch_bounds__(256) void proj_g(
    const us* __restrict__ A, const void* __restrict__ W, void* __restrict__ C,
    const int* __restrict__ flagp)
{
    if (*flagp) gemm128_body<1, 1>(A, W, C);
    else        gemm128_body<1, 0>(A, W, C);
}

__global__ __launch_bounds__(256) void attn_m(
    const us* __restrict__ Q, const us* __restrict__ K,
    const us* __restrict__ V, us* __restrict__ O)
{
    const int qt = 15 - blockIdx.x;
    const int bh = blockIdx.y;
    const int q0 = qt * 64;
    const size_t base = (size_t)bh * T_ * HS_;
    const int tid  = threadIdx.x;
    const int w    = tid >> 6;
    const int lane = tid & 63;
    const int quad = lane >> 4;
    const int l15  = lane & 15;

    __shared__ __align__(16) us vt[64][72];
    __shared__ __align__(16) us ps[4][16][72];

    bf16x8 qf[2];
    {
        const us* qp = Q + base + (size_t)(q0 + w * 16 + l15) * HS_ + quad * 8;
        qf[0] = *reinterpret_cast<const bf16x8*>(qp);
        qf[1] = *reinterpret_cast<const bf16x8*>(qp + 32);
    }

    float m_i[4], l_i[4];
    f32x4 oacc[4] = {};
#pragma unroll
    for (int r = 0; r < 4; ++r) { m_i[r] = -1e30f; l_i[r] = 0.f; }

    const int vs  = lane;
    const int vd0 = w * 16;
    const int nch = qt + 1;
    for (int ch = 0; ch < nch; ++ch) {
        const int s0 = ch * 64;
        __syncthreads();
        {
            const us* vp = V + base + (size_t)(s0 + vs) * HS_ + vd0;
            union { bf16x8 v; us u[8]; } a, b;
            a.v = *reinterpret_cast<const bf16x8*>(vp);
            b.v = *reinterpret_cast<const bf16x8*>(vp + 8);
#pragma unroll
            for (int j = 0; j < 8; ++j) vt[vd0 + j][vs]     = a.u[j];
#pragma unroll
            for (int j = 0; j < 8; ++j) vt[vd0 + 8 + j][vs] = b.u[j];
        }
        bf16x8 kf[4][2];
#pragma unroll
        for (int nt = 0; nt < 4; ++nt) {
            const us* kp = K + base + (size_t)(s0 + nt * 16 + l15) * HS_ + quad * 8;
            kf[nt][0] = *reinterpret_cast<const bf16x8*>(kp);
            kf[nt][1] = *reinterpret_cast<const bf16x8*>(kp + 32);
        }
        f32x4 sacc[4] = {};
#pragma unroll
        for (int nt = 0; nt < 4; ++nt) {
            sacc[nt] = __builtin_amdgcn_mfma_f32_16x16x32_bf16(qf[0], kf[nt][0], sacc[nt], 0, 0, 0);
            sacc[nt] = __builtin_amdgcn_mfma_f32_16x16x32_bf16(qf[1], kf[nt][1], sacc[nt], 0, 0, 0);
        }
        __syncthreads();
        const int rowg = q0 + w * 16 + quad * 4;
        if (ch == nch - 1) {
#pragma unroll
            for (int nt = 0; nt < 4; ++nt)
#pragma unroll
                for (int r = 0; r < 4; ++r)
                    if (s0 + nt * 16 + l15 > rowg + r) sacc[nt][r] = -1e30f;
        }
#pragma unroll
        for (int r = 0; r < 4; ++r) {
            float mx = fmaxf(fmaxf(sacc[0][r], sacc[1][r]), fmaxf(sacc[2][r], sacc[3][r]));
            mx = fmaxf(mx, __shfl_xor(mx, 1));
            mx = fmaxf(mx, __shfl_xor(mx, 2));
            mx = fmaxf(mx, __shfl_xor(mx, 4));
            mx = fmaxf(mx, __shfl_xor(mx, 8));
            const float mnew  = fmaxf(m_i[r], mx);
            const float alpha = exp2f((m_i[r] - mnew) * CSCALE);
            m_i[r] = mnew;
            float sum = 0.f;
#pragma unroll
            for (int nt = 0; nt < 4; ++nt) {
                const float p = exp2f((sacc[nt][r] - mnew) * CSCALE);
                sum += p;
                ps[w][quad * 4 + r][nt * 16 + l15] = f2bf(p);
            }
            sum += __shfl_xor(sum, 1);
            sum += __shfl_xor(sum, 2);
            sum += __shfl_xor(sum, 4);
            sum += __shfl_xor(sum, 8);
            l_i[r] = l_i[r] * alpha + sum;
#pragma unroll
            for (int nt = 0; nt < 4; ++nt) oacc[nt][r] *= alpha;
        }
        bf16x8 pf[2];
        pf[0] = *reinterpret_cast<const bf16x8*>(&ps[w][l15][quad * 8]);
        pf[1] = *reinterpret_cast<const bf16x8*>(&ps[w][l15][quad * 8 + 32]);
#pragma unroll
        for (int nt = 0; nt < 4; ++nt) {
            bf16x8 vf0 = *reinterpret_cast<const bf16x8*>(&vt[nt * 16 + l15][quad * 8]);
            bf16x8 vf1 = *reinterpret_cast<const bf16x8*>(&vt[nt * 16 + l15][quad * 8 + 32]);
            oacc[nt] = __builtin_amdgcn_mfma_f32_16x16x32_bf16(pf[0], vf0, oacc[nt], 0, 0, 0);
            oacc[nt] = __builtin_amdgcn_mfma_f32_16x16x32_bf16(pf[1], vf1, oacc[nt], 0, 0, 0);
        }
    }
    const int b = bh >> 4, h = bh & 15;
    const int trow = q0 + w * 16 + quad * 4;
#pragma unroll
    for (int r = 0; r < 4; ++r) {
        const float inv = 1.f / l_i[r];
        const size_t off = ((size_t)b * T_ + trow + r) * E_ + h * HS_;
#pragma unroll
        for (int nt = 0; nt < 4; ++nt)
            O[off + nt * 16 + l15] = f2bf(oacc[nt][r] * inv);
    }
}

// ===========================================================================
extern "C" void kernel_launch(void* const* d_in, const int* in_sizes, int n_in,
                              void* d_out, int out_size, void* d_ws, size_t ws_size,
                              hipStream_t stream) {
    // setup_inputs order: x, Wk, Wq, Wv, Wproj, i
    const void* x  = d_in[0];
    const void* Wk = d_in[1];
    const void* Wq = d_in[2];
    const void* Wv = d_in[3];
    const void* Wp = d_in[4];

    const size_t qe = (size_t)B_ * H_ * T_ * HS_;   // 8,388,608 elems
    const size_t we = (size_t)E_ * E_;              // 1,048,576 elems
    int* flag = (int*)d_ws;

    const size_t NEED_FAST = 256 + (4 * qe + 4 * we) * sizeof(us);   // ~72 MB

    detect_kernel<<<1, 256, 0, stream>>>((const us*)x, flag);

    if (ws_size >= NEED_FAST) {
        us* xb = (us*)((char*)d_ws + 256);
        us* wq = xb + qe;
        us* wk = wq + we;
        us* wv = wk + we;
        us* wp = wv + we;
        us* q  = wp + we;
        us* k  = q + qe;
        us* vT = k + qe;
        us* o  = xb;   // xb dead after qkv_gf

        cvt_kernel<<<dim3(4096, 5), 256, 0, stream>>>(x, Wq, Wk, Wv, Wp,
                                                      xb, wq, wk, wv, wp, flag);
        qkv_gf<<<dim3(64, 8, 3), 256, 0, stream>>>(xb, wq, wk, wv, q, k, vT);
        attn_v3<<<dim3(8, 128), 256, 0, stream>>>(q, k, vT, o);
        proj_gf<<<dim3(64, 8), 256, 0, stream>>>(o, wp, d_out, flag);
    } else {
        // r6 fallback (64 MB ws)
        us* q = (us*)((char*)d_ws + 256);
        us* k = q + qe;
        us* v = k + qe;
        us* o = v + qe;
        qkv_g<<<dim3(64, 8, 3), 256, 0, stream>>>(x, Wq, Wk, Wv, q, k, v, flag);
        attn_m<<<dim3(16, 128), 256, 0, stream>>>(q, k, v, o);
        proj_g<<<dim3(64, 8), 256, 0, stream>>>(o, Wp, d_out, flag);
    }
}

// Round 9
// 298.778 us; speedup vs baseline: 1.4827x; 1.1493x over previous
//
#include <hip/hip_runtime.h>

// (B,T,E,H,HS) = (8,1024,1024,16,64). Inputs/output: float32 (r6-r8 proven,
// flag=1 path). Internals bf16 MFMA. Fast path needs ~72 MB ws; r6-verbatim
// fallback otherwise.
#define B_  8
#define T_  1024
#define E_  1024
#define H_  16
#define HS_ 64
#define K_  1024

typedef __bf16 bf16x8 __attribute__((ext_vector_type(8)));
typedef float  f32x4  __attribute__((ext_vector_type(4)));
typedef unsigned short us;

__device__ __forceinline__ float bf2f(us u) {
    union { unsigned int i; float f; } c; c.i = ((unsigned int)u) << 16; return c.f;
}
__device__ __forceinline__ us f2bf(float f) {
    union { float f; unsigned int i; } c; c.f = f;
    unsigned int x = c.i;
    return (us)((x + 0x7fff + ((x >> 16) & 1)) >> 16);  // RNE
}
__device__ __forceinline__ bf16x8 cvt8(const float* p) {
    float4 a = *reinterpret_cast<const float4*>(p);
    float4 b = *reinterpret_cast<const float4*>(p + 4);
    union { bf16x8 v; us u[8]; } c;
    c.u[0] = f2bf(a.x); c.u[1] = f2bf(a.y); c.u[2] = f2bf(a.z); c.u[3] = f2bf(a.w);
    c.u[4] = f2bf(b.x); c.u[5] = f2bf(b.y); c.u[6] = f2bf(b.z); c.u[7] = f2bf(b.w);
    return c.v;
}
// Async global->LDS 16B/lane; LDS dest = wave-uniform base + lane*16 (m97/m104).
__device__ __forceinline__ void async_cp16(const us* g, us* l) {
    __builtin_amdgcn_global_load_lds((const unsigned int*)g, (unsigned int*)l, 16, 0, 0);
}

// Dtype probe (r2/r6-proven). flag=1 => float32 inputs.
__global__ void detect_kernel(const us* __restrict__ x, int* __restrict__ flag) {
    const int t = threadIdx.x;
    int maxe = 0;
    for (int s = 0; s < 8; ++s) {
        us u = x[2 * (t + 256 * s)];
        maxe = max(maxe, (int)((u >> 7) & 0xFF));
    }
    __shared__ int red[256];
    red[t] = maxe;
    __syncthreads();
    for (int off = 128; off > 0; off >>= 1) {
        if (t < off) red[t] = max(red[t], red[t + off]);
        __syncthreads();
    }
    if (t == 0) *flag = (red[0] > 140) ? 1 : 0;
}

// ===========================================================================
// FAST PATH
// ===========================================================================
__global__ __launch_bounds__(256) void cvt_kernel(
    const void* __restrict__ sx, const void* __restrict__ sq,
    const void* __restrict__ sk, const void* __restrict__ sv,
    const void* __restrict__ sp,
    us* __restrict__ dx, us* __restrict__ dq, us* __restrict__ dk,
    us* __restrict__ dv, us* __restrict__ dp, const int* __restrict__ flagp)
{
    const int y = blockIdx.y;
    const void* src = (y == 0) ? sx : (y == 1) ? sq : (y == 2) ? sk : (y == 3) ? sv : sp;
    us*         dst = (y == 0) ? dx : (y == 1) ? dq : (y == 2) ? dk : (y == 3) ? dv : dp;
    const size_t n = (y == 0) ? (size_t)B_ * T_ * E_ : (size_t)E_ * E_;
    const size_t i = ((size_t)blockIdx.x * 256 + threadIdx.x) * 8;
    if (i >= n) return;
    if (*flagp) *reinterpret_cast<bf16x8*>(dst + i) = cvt8((const float*)src + i);
    else        *reinterpret_cast<bf16x8*>(dst + i) =
                    *reinterpret_cast<const bf16x8*>((const us*)src + i);
}

// 128x128 all-bf16 GEMM with global_load_lds width-16 staging (r8-proven).
__global__ __launch_bounds__(256) void qkv_gf(
    const us* __restrict__ A,
    const us* __restrict__ Wq, const us* __restrict__ Wk, const us* __restrict__ Wv,
    us* __restrict__ q, us* __restrict__ k, us* __restrict__ vT)
{
    const int type = blockIdx.z;
    const us* Bm = (type == 0) ? Wq : (type == 1) ? Wk : Wv;
    us* out      = (type == 0) ? q  : (type == 1) ? k  : vT;
    const int vtrans = (type == 2);

    __shared__ us As[128 * 32];
    __shared__ us Bs[128 * 32];

    const int tid  = threadIdx.x;
    const int lane = tid & 63;
    const int w    = tid >> 6;
    const int quad = lane >> 4;
    const int l15  = lane & 15;
    const int wm   = w >> 1, wn = w & 1;
    const int row0 = blockIdx.x * 128;
    const int col0 = blockIdx.y * 128;

    f32x4 acc[4][4] = {};
    for (int k0 = 0; k0 < K_; k0 += 32) {
        __syncthreads();
#pragma unroll
        for (int i = 0; i < 2; ++i) {
            const int idx = tid + i * 256;
            const int r   = idx >> 2;
            const int c8  = (idx & 3) * 8;
            async_cp16(A  + (size_t)(row0 + r) * K_ + k0 + c8, &As[r * 32 + c8]);
            async_cp16(Bm + (size_t)(col0 + r) * K_ + k0 + c8, &Bs[r * 32 + c8]);
        }
        __syncthreads();
        bf16x8 af[4], bf[4];
#pragma unroll
        for (int t = 0; t < 4; ++t) {
            af[t] = *reinterpret_cast<const bf16x8*>(&As[(wm * 64 + t * 16 + l15) * 32 + quad * 8]);
            bf[t] = *reinterpret_cast<const bf16x8*>(&Bs[(wn * 64 + t * 16 + l15) * 32 + quad * 8]);
        }
#pragma unroll
        for (int mt = 0; mt < 4; ++mt)
#pragma unroll
            for (int nt = 0; nt < 4; ++nt)
                acc[mt][nt] = __builtin_amdgcn_mfma_f32_16x16x32_bf16(af[mt], bf[nt], acc[mt][nt], 0, 0, 0);
    }

#pragma unroll
    for (int mt = 0; mt < 4; ++mt)
#pragma unroll
        for (int nt = 0; nt < 4; ++nt)
#pragma unroll
            for (int r = 0; r < 4; ++r) {
                const int m = row0 + wm * 64 + mt * 16 + quad * 4 + r;
                const int n = col0 + wn * 64 + nt * 16 + l15;
                const int b = m >> 10, t = m & 1023;
                const int h = n >> 6,  d = n & 63;
                const us vb = f2bf(acc[mt][nt][r]);
                if (vtrans)  out[((size_t)((b * 16 + h) * 64 + d)) * 1024 + t] = vb;
                else         out[((size_t)(b * 16 + h) * 1024 + t) * 64 + d] = vb;
            }
}

__global__ __launch_bounds__(256) void proj_gf(
    const us* __restrict__ A, const us* __restrict__ Bm, void* __restrict__ C,
    const int* __restrict__ flagp)
{
    __shared__ us As[128 * 32];
    __shared__ us Bs[128 * 32];

    const int tid  = threadIdx.x;
    const int lane = tid & 63;
    const int w    = tid >> 6;
    const int quad = lane >> 4;
    const int l15  = lane & 15;
    const int wm   = w >> 1, wn = w & 1;
    const int row0 = blockIdx.x * 128;
    const int col0 = blockIdx.y * 128;
    const int cf32 = *flagp;

    f32x4 acc[4][4] = {};
    for (int k0 = 0; k0 < K_; k0 += 32) {
        __syncthreads();
#pragma unroll
        for (int i = 0; i < 2; ++i) {
            const int idx = tid + i * 256;
            const int r   = idx >> 2;
            const int c8  = (idx & 3) * 8;
            async_cp16(A  + (size_t)(row0 + r) * K_ + k0 + c8, &As[r * 32 + c8]);
            async_cp16(Bm + (size_t)(col0 + r) * K_ + k0 + c8, &Bs[r * 32 + c8]);
        }
        __syncthreads();
        bf16x8 af[4], bf[4];
#pragma unroll
        for (int t = 0; t < 4; ++t) {
            af[t] = *reinterpret_cast<const bf16x8*>(&As[(wm * 64 + t * 16 + l15) * 32 + quad * 8]);
            bf[t] = *reinterpret_cast<const bf16x8*>(&Bs[(wn * 64 + t * 16 + l15) * 32 + quad * 8]);
        }
#pragma unroll
        for (int mt = 0; mt < 4; ++mt)
#pragma unroll
            for (int nt = 0; nt < 4; ++nt)
                acc[mt][nt] = __builtin_amdgcn_mfma_f32_16x16x32_bf16(af[mt], bf[nt], acc[mt][nt], 0, 0, 0);
    }

#pragma unroll
    for (int mt = 0; mt < 4; ++mt)
#pragma unroll
        for (int nt = 0; nt < 4; ++nt)
#pragma unroll
            for (int r = 0; r < 4; ++r) {
                const int m = row0 + wm * 64 + mt * 16 + quad * 4 + r;
                const int n = col0 + wn * 64 + nt * 16 + l15;
                const size_t off = (size_t)m * E_ + n;
                if (cf32) ((float*)C)[off] = acc[mt][nt][r];
                else      ((us*)C)[off] = f2bf(acc[mt][nt][r]);
            }
}

// ---------------------------------------------------------------------------
// attn_v4: causal-paired q-tiles for uniform per-block work.
// Block p handles q-tiles p and 15-p (64 rows each): (p+1)+(16-p)=17 units.
// Wave w owns 16 rows of each tile. K + V^T chunks staged in LDS; per-wave
// ps buffer reused sequentially for the two tiles (wave-internal DS order).
// ---------------------------------------------------------------------------
#define CSCALE 0.18033688011112042f   // 0.125 * log2(e)

struct TileSt {
    bf16x8 qf[2];
    float  m_i[4], l_i[4];
    f32x4  oacc[4];
};

__device__ __forceinline__ void tile_step(
    TileSt& ts, const us (*kt)[72], const us (*vt)[72], us (*psw)[72],
    int s0, int rowlo, int quad, int l15, bool diag)
{
    // S = Q.K^T
    f32x4 sacc[4] = {};
#pragma unroll
    for (int nt = 0; nt < 4; ++nt) {
        bf16x8 kf0 = *reinterpret_cast<const bf16x8*>(&kt[nt * 16 + l15][quad * 8]);
        bf16x8 kf1 = *reinterpret_cast<const bf16x8*>(&kt[nt * 16 + l15][quad * 8 + 32]);
        sacc[nt] = __builtin_amdgcn_mfma_f32_16x16x32_bf16(ts.qf[0], kf0, sacc[nt], 0, 0, 0);
        sacc[nt] = __builtin_amdgcn_mfma_f32_16x16x32_bf16(ts.qf[1], kf1, sacc[nt], 0, 0, 0);
    }
    if (diag) {
#pragma unroll
        for (int nt = 0; nt < 4; ++nt)
#pragma unroll
            for (int r = 0; r < 4; ++r)
                if (s0 + nt * 16 + l15 > rowlo + quad * 4 + r) sacc[nt][r] = -1e30f;
    }
    // online softmax (row r lives in lanes quad*4+r across 16 l15 lanes)
#pragma unroll
    for (int r = 0; r < 4; ++r) {
        float mx = fmaxf(fmaxf(sacc[0][r], sacc[1][r]), fmaxf(sacc[2][r], sacc[3][r]));
        mx = fmaxf(mx, __shfl_xor(mx, 1));
        mx = fmaxf(mx, __shfl_xor(mx, 2));
        mx = fmaxf(mx, __shfl_xor(mx, 4));
        mx = fmaxf(mx, __shfl_xor(mx, 8));
        const float mnew  = fmaxf(ts.m_i[r], mx);
        const float alpha = exp2f((ts.m_i[r] - mnew) * CSCALE);
        ts.m_i[r] = mnew;
        float sum = 0.f;
#pragma unroll
        for (int nt = 0; nt < 4; ++nt) {
            const float p = exp2f((sacc[nt][r] - mnew) * CSCALE);
            sum += p;
            psw[quad * 4 + r][nt * 16 + l15] = f2bf(p);
        }
        sum += __shfl_xor(sum, 1);
        sum += __shfl_xor(sum, 2);
        sum += __shfl_xor(sum, 4);
        sum += __shfl_xor(sum, 8);
        ts.l_i[r] = ts.l_i[r] * alpha + sum;
#pragma unroll
        for (int dt = 0; dt < 4; ++dt) ts.oacc[dt][r] *= alpha;
    }
    // P C-layout -> A-layout via per-wave LDS; O += P.V
    bf16x8 pf0 = *reinterpret_cast<const bf16x8*>(&psw[l15][quad * 8]);
    bf16x8 pf1 = *reinterpret_cast<const bf16x8*>(&psw[l15][quad * 8 + 32]);
#pragma unroll
    for (int dt = 0; dt < 4; ++dt) {
        bf16x8 vf0 = *reinterpret_cast<const bf16x8*>(&vt[dt * 16 + l15][quad * 8]);
        bf16x8 vf1 = *reinterpret_cast<const bf16x8*>(&vt[dt * 16 + l15][quad * 8 + 32]);
        ts.oacc[dt] = __builtin_amdgcn_mfma_f32_16x16x32_bf16(pf0, vf0, ts.oacc[dt], 0, 0, 0);
        ts.oacc[dt] = __builtin_amdgcn_mfma_f32_16x16x32_bf16(pf1, vf1, ts.oacc[dt], 0, 0, 0);
    }
}

__global__ __launch_bounds__(256) void attn_v4(
    const us* __restrict__ Q, const us* __restrict__ K,
    const us* __restrict__ VT, us* __restrict__ O)
{
    const int px = blockIdx.x;          // 0..7
    const int bh = blockIdx.y;
    const int tA = px, tB = 15 - px;    // paired q-tiles: work = 17 units, uniform
    const size_t base  = (size_t)bh * T_ * HS_;
    const size_t baseT = (size_t)bh * HS_ * T_;
    const int tid  = threadIdx.x;
    const int w    = tid >> 6;
    const int lane = tid & 63;
    const int quad = lane >> 4;
    const int l15  = lane & 15;

    __shared__ __align__(16) us kt[64][72];
    __shared__ __align__(16) us vt[64][72];
    __shared__ __align__(16) us ps[4][16][72];

    const int rowA = tA * 64 + w * 16;  // wave's 16 rows in tile A
    const int rowB = tB * 64 + w * 16;

    TileSt A, B;
    {
        const us* qa = Q + base + (size_t)(rowA + l15) * HS_ + quad * 8;
        const us* qb = Q + base + (size_t)(rowB + l15) * HS_ + quad * 8;
        A.qf[0] = *reinterpret_cast<const bf16x8*>(qa);
        A.qf[1] = *reinterpret_cast<const bf16x8*>(qa + 32);
        B.qf[0] = *reinterpret_cast<const bf16x8*>(qb);
        B.qf[1] = *reinterpret_cast<const bf16x8*>(qb + 32);
    }
#pragma unroll
    for (int r = 0; r < 4; ++r) {
        A.m_i[r] = -1e30f; A.l_i[r] = 0.f;
        B.m_i[r] = -1e30f; B.l_i[r] = 0.f;
#pragma unroll
        for (int dt = 0; dt < 4; ++dt) { A.oacc[dt][r] = 0.f; B.oacc[dt][r] = 0.f; }
    }

    const int nch = tB + 1;             // 16 - px chunks (tile A's ⊆ tile B's)
    for (int ch = 0; ch < nch; ++ch) {
        const int s0 = ch * 64;
        __syncthreads();                // prior chunk's LDS readers done
#pragma unroll
        for (int i = 0; i < 2; ++i) {   // stage 64x64 K and V^T
            const int idx = tid + i * 256;
            const int r   = idx >> 3;
            const int c8  = (idx & 7) * 8;
            *reinterpret_cast<bf16x8*>(&kt[r][c8]) =
                *reinterpret_cast<const bf16x8*>(K + base + (size_t)(s0 + r) * HS_ + c8);
            *reinterpret_cast<bf16x8*>(&vt[r][c8]) =
                *reinterpret_cast<const bf16x8*>(VT + baseT + (size_t)r * T_ + s0 + c8);
        }
        __syncthreads();

        tile_step(B, kt, vt, ps[w], s0, rowB, quad, l15, ch == tB);
        if (ch <= tA)
            tile_step(A, kt, vt, ps[w], s0, rowA, quad, l15, ch == tA);
    }

    // epilogue: normalize, concat-head bf16 ws [b][t][h*HS+d]
    const int b = bh >> 4, h = bh & 15;
#pragma unroll
    for (int r = 0; r < 4; ++r) {
        const float invA = 1.f / A.l_i[r];
        const float invB = 1.f / B.l_i[r];
        const size_t offA = ((size_t)b * T_ + rowA + quad * 4 + r) * E_ + h * HS_;
        const size_t offB = ((size_t)b * T_ + rowB + quad * 4 + r) * E_ + h * HS_;
#pragma unroll
        for (int dt = 0; dt < 4; ++dt) {
            O[offA + dt * 16 + l15] = f2bf(A.oacc[dt][r] * invA);
            O[offB + dt * 16 + l15] = f2bf(B.oacc[dt][r] * invB);
        }
    }
}

// ===========================================================================
// FALLBACK (r6 verbatim) — used when ws_size < fast-path need
// ===========================================================================
template <int MODE, int F32>
__device__ __forceinline__ void gemm128_body(
    const void* __restrict__ A, const void* __restrict__ Bm, void* __restrict__ out)
{
    __shared__ us As[128 * 32];
    __shared__ us Bs[128 * 32];

    const int tid  = threadIdx.x;
    const int lane = tid & 63;
    const int w    = tid >> 6;
    const int quad = lane >> 4;
    const int l15  = lane & 15;
    const int wm   = w >> 1, wn = w & 1;
    const int row0 = blockIdx.x * 128;
    const int col0 = blockIdx.y * 128;

    f32x4 acc[4][4] = {};
    for (int k0 = 0; k0 < K_; k0 += 32) {
        __syncthreads();
#pragma unroll
        for (int i = 0; i < 2; ++i) {
            const int idx = tid + i * 256;
            const int r   = idx >> 2;
            const int c8  = (idx & 3) * 8;
            bf16x8 av, bv;
            if constexpr (MODE == 0) {
                if constexpr (F32) av = cvt8((const float*)A + (size_t)(row0 + r) * K_ + k0 + c8);
                else av = *reinterpret_cast<const bf16x8*>((const us*)A + (size_t)(row0 + r) * K_ + k0 + c8);
            } else {
                av = *reinterpret_cast<const bf16x8*>((const us*)A + (size_t)(row0 + r) * K_ + k0 + c8);
            }
            if constexpr (F32) bv = cvt8((const float*)Bm + (size_t)(col0 + r) * K_ + k0 + c8);
            else bv = *reinterpret_cast<const bf16x8*>((const us*)Bm + (size_t)(col0 + r) * K_ + k0 + c8);
            *reinterpret_cast<bf16x8*>(&As[r * 32 + c8]) = av;
            *reinterpret_cast<bf16x8*>(&Bs[r * 32 + c8]) = bv;
        }
        __syncthreads();
        bf16x8 af[4], bf[4];
#pragma unroll
        for (int t = 0; t < 4; ++t) {
            af[t] = *reinterpret_cast<const bf16x8*>(&As[(wm * 64 + t * 16 + l15) * 32 + quad * 8]);
            bf[t] = *reinterpret_cast<const bf16x8*>(&Bs[(wn * 64 + t * 16 + l15) * 32 + quad * 8]);
        }
#pragma unroll
        for (int mt = 0; mt < 4; ++mt)
#pragma unroll
            for (int nt = 0; nt < 4; ++nt)
                acc[mt][nt] = __builtin_amdgcn_mfma_f32_16x16x32_bf16(af[mt], bf[nt], acc[mt][nt], 0, 0, 0);
    }
#pragma unroll
    for (int mt = 0; mt < 4; ++mt)
#pragma unroll
        for (int nt = 0; nt < 4; ++nt)
#pragma unroll
            for (int r = 0; r < 4; ++r) {
                const int m = row0 + wm * 64 + mt * 16 + quad * 4 + r;
                const int n = col0 + wn * 64 + nt * 16 + l15;
                const float val = acc[mt][nt][r];
                if constexpr (MODE == 0) {
                    const int b = m >> 10, t = m & 1023;
                    const int h = n >> 6,  d = n & 63;
                    ((us*)out)[((size_t)(b * 16 + h) * 1024 + t) * 64 + d] = f2bf(val);
                } else {
                    if constexpr (F32) ((float*)out)[(size_t)m * E_ + n] = val;
                    else               ((us*)out)[(size_t)m * E_ + n] = f2bf(val);
                }
            }
}

__global__ __launch_bounds__(256) void qkv_g(
    const void* __restrict__ x,
    const void* __restrict__ Wq, const void* __restrict__ Wk, const void* __restrict__ Wv,
    us* __restrict__ q, us* __restrict__ k, us* __restrict__ v,
    const int* __restrict__ flagp)
{
    const int type = blockIdx.z;
    const void* W = (type == 0) ? Wq : (type == 1) ? Wk : Wv;
    us* out       = (type == 0) ? q  : (type == 1) ? k  : v;
    if (*flagp) gemm128_body<0, 1>(x, W, out);
    else        gemm128_body<0, 0>(x, W, out);
}

__global__ __launch_bounds__(256) void proj_g(
    const us* __restrict__ A, const void* __restrict__ W, void* __restrict__ C,
    const int* __restrict__ flagp)
{
    if (*flagp) gemm128_body<1, 1>(A, W, C);
    else        gemm128_body<1, 0>(A, W, C);
}

__global__ __launch_bounds__(256) void attn_m(
    const us* __restrict__ Q, const us* __restrict__ K,
    const us* __restrict__ V, us* __restrict__ O)
{
    const int qt = 15 - blockIdx.x;
    const int bh = blockIdx.y;
    const int q0 = qt * 64;
    const size_t base = (size_t)bh * T_ * HS_;
    const int tid  = threadIdx.x;
    const int w    = tid >> 6;
    const int lane = tid & 63;
    const int quad = lane >> 4;
    const int l15  = lane & 15;

    __shared__ __align__(16) us vt[64][72];
    __shared__ __align__(16) us ps[4][16][72];

    bf16x8 qf[2];
    {
        const us* qp = Q + base + (size_t)(q0 + w * 16 + l15) * HS_ + quad * 8;
        qf[0] = *reinterpret_cast<const bf16x8*>(qp);
        qf[1] = *reinterpret_cast<const bf16x8*>(qp + 32);
    }

    float m_i[4], l_i[4];
    f32x4 oacc[4] = {};
#pragma unroll
    for (int r = 0; r < 4; ++r) { m_i[r] = -1e30f; l_i[r] = 0.f; }

    const int vs  = lane;
    const int vd0 = w * 16;
    const int nch = qt + 1;
    for (int ch = 0; ch < nch; ++ch) {
        const int s0 = ch * 64;
        __syncthreads();
        {
            const us* vp = V + base + (size_t)(s0 + vs) * HS_ + vd0;
            union { bf16x8 v; us u[8]; } a, b;
            a.v = *reinterpret_cast<const bf16x8*>(vp);
            b.v = *reinterpret_cast<const bf16x8*>(vp + 8);
#pragma unroll
            for (int j = 0; j < 8; ++j) vt[vd0 + j][vs]     = a.u[j];
#pragma unroll
            for (int j = 0; j < 8; ++j) vt[vd0 + 8 + j][vs] = b.u[j];
        }
        bf16x8 kf[4][2];
#pragma unroll
        for (int nt = 0; nt < 4; ++nt) {
            const us* kp = K + base + (size_t)(s0 + nt * 16 + l15) * HS_ + quad * 8;
            kf[nt][0] = *reinterpret_cast<const bf16x8*>(kp);
            kf[nt][1] = *reinterpret_cast<const bf16x8*>(kp + 32);
        }
        f32x4 sacc[4] = {};
#pragma unroll
        for (int nt = 0; nt < 4; ++nt) {
            sacc[nt] = __builtin_amdgcn_mfma_f32_16x16x32_bf16(qf[0], kf[nt][0], sacc[nt], 0, 0, 0);
            sacc[nt] = __builtin_amdgcn_mfma_f32_16x16x32_bf16(qf[1], kf[nt][1], sacc[nt], 0, 0, 0);
        }
        __syncthreads();
        const int rowg = q0 + w * 16 + quad * 4;
        if (ch == nch - 1) {
#pragma unroll
            for (int nt = 0; nt < 4; ++nt)
#pragma unroll
                for (int r = 0; r < 4; ++r)
                    if (s0 + nt * 16 + l15 > rowg + r) sacc[nt][r] = -1e30f;
        }
#pragma unroll
        for (int r = 0; r < 4; ++r) {
            float mx = fmaxf(fmaxf(sacc[0][r], sacc[1][r]), fmaxf(sacc[2][r], sacc[3][r]));
            mx = fmaxf(mx, __shfl_xor(mx, 1));
            mx = fmaxf(mx, __shfl_xor(mx, 2));
            mx = fmaxf(mx, __shfl_xor(mx, 4));
            mx = fmaxf(mx, __shfl_xor(mx, 8));
            const float mnew  = fmaxf(m_i[r], mx);
            const float alpha = exp2f((m_i[r] - mnew) * CSCALE);
            m_i[r] = mnew;
            float sum = 0.f;
#pragma unroll
            for (int nt = 0; nt < 4; ++nt) {
                const float p = exp2f((sacc[nt][r] - mnew) * CSCALE);
                sum += p;
                ps[w][quad * 4 + r][nt * 16 + l15] = f2bf(p);
            }
            sum += __shfl_xor(sum, 1);
            sum += __shfl_xor(sum, 2);
            sum += __shfl_xor(sum, 4);
            sum += __shfl_xor(sum, 8);
            l_i[r] = l_i[r] * alpha + sum;
#pragma unroll
            for (int nt = 0; nt < 4; ++nt) oacc[nt][r] *= alpha;
        }
        bf16x8 pf[2];
        pf[0] = *reinterpret_cast<const bf16x8*>(&ps[w][l15][quad * 8]);
        pf[1] = *reinterpret_cast<const bf16x8*>(&ps[w][l15][quad * 8 + 32]);
#pragma unroll
        for (int nt = 0; nt < 4; ++nt) {
            bf16x8 vf0 = *reinterpret_cast<const bf16x8*>(&vt[nt * 16 + l15][quad * 8]);
            bf16x8 vf1 = *reinterpret_cast<const bf16x8*>(&vt[nt * 16 + l15][quad * 8 + 32]);
            oacc[nt] = __builtin_amdgcn_mfma_f32_16x16x32_bf16(pf[0], vf0, oacc[nt], 0, 0, 0);
            oacc[nt] = __builtin_amdgcn_mfma_f32_16x16x32_bf16(pf[1], vf1, oacc[nt], 0, 0, 0);
        }
    }
    const int b = bh >> 4, h = bh & 15;
    const int trow = q0 + w * 16 + quad * 4;
#pragma unroll
    for (int r = 0; r < 4; ++r) {
        const float inv = 1.f / l_i[r];
        const size_t off = ((size_t)b * T_ + trow + r) * E_ + h * HS_;
#pragma unroll
        for (int nt = 0; nt < 4; ++nt)
            O[off + nt * 16 + l15] = f2bf(oacc[nt][r] * inv);
    }
}

// ===========================================================================
extern "C" void kernel_launch(void* const* d_in, const int* in_sizes, int n_in,
                              void* d_out, int out_size, void* d_ws, size_t ws_size,
                              hipStream_t stream) {
    // setup_inputs order: x, Wk, Wq, Wv, Wproj, i
    const void* x  = d_in[0];
    const void* Wk = d_in[1];
    const void* Wq = d_in[2];
    const void* Wv = d_in[3];
    const void* Wp = d_in[4];

    const size_t qe = (size_t)B_ * H_ * T_ * HS_;   // 8,388,608 elems
    const size_t we = (size_t)E_ * E_;              // 1,048,576 elems
    int* flag = (int*)d_ws;

    const size_t NEED_FAST = 256 + (4 * qe + 4 * we) * sizeof(us);   // ~72 MB

    detect_kernel<<<1, 256, 0, stream>>>((const us*)x, flag);

    if (ws_size >= NEED_FAST) {
        us* xb = (us*)((char*)d_ws + 256);
        us* wq = xb + qe;
        us* wk = wq + we;
        us* wv = wk + we;
        us* wp = wv + we;
        us* q  = wp + we;
        us* k  = q + qe;
        us* vT = k + qe;
        us* o  = xb;   // xb dead after qkv_gf

        cvt_kernel<<<dim3(4096, 5), 256, 0, stream>>>(x, Wq, Wk, Wv, Wp,
                                                      xb, wq, wk, wv, wp, flag);
        qkv_gf<<<dim3(64, 8, 3), 256, 0, stream>>>(xb, wq, wk, wv, q, k, vT);
        attn_v4<<<dim3(8, 128), 256, 0, stream>>>(q, k, vT, o);
        proj_gf<<<dim3(64, 8), 256, 0, stream>>>(o, wp, d_out, flag);
    } else {
        // r6 fallback (64 MB ws)
        us* q = (us*)((char*)d_ws + 256);
        us* k = q + qe;
        us* v = k + qe;
        us* o = v + qe;
        qkv_g<<<dim3(64, 8, 3), 256, 0, stream>>>(x, Wq, Wk, Wv, q, k, v, flag);
        attn_m<<<dim3(16, 128), 256, 0, stream>>>(q, k, v, o);
        proj_g<<<dim3(64, 8), 256, 0, stream>>>(o, Wp, d_out, flag);
    }
}